// Round 1
// baseline (97.341 us; speedup 1.0000x reference)
//
#include <hip/hip_runtime.h>
#include <math.h>

#define NV 512
#define KC 32
#define NB 192
#define LOG2PI 1.8378770664093453f

// ws float layout:
// [0..512)    assign (int view)
// [512..544)  coef[32]
// [544]       logdet
// [545]       XXsum   (sum_i sum_n X^2)
// [546]       MMsum   (sum_j sum_n mean^2)
// [548..580)  SX1[32] (sum_i sx[i][c])
// [580..612)  SX2[32] (sum_i sx[i][c]^2)
// [676..1188) u[512]  (col sums of X)
// [1188..1700) v[512] (col sums of mean)
// [1700..7844) sm[192][32] (cluster row-sums of mean)
#define WS_COEF 512
#define WS_LOGDET 544
#define WS_XX 545
#define WS_MM 546
#define WS_SX1 548
#define WS_SX2 580
#define WS_U 676
#define WS_V 1188
#define WS_SM 1700
#define WS_TOTAL 7844

__global__ __launch_bounds__(256) void fused_kernel(
    const float* __restrict__ X, const float* __restrict__ C,
    const float* __restrict__ G, const float* __restrict__ W,
    const float* __restrict__ bias, const float* __restrict__ sigma,
    const float* __restrict__ rho, float* __restrict__ wsF, int* __restrict__ wsI)
{
    const int bid = blockIdx.x;
    const int tid = threadIdx.x;
    __shared__ int asg[NV];
    // every block computes assign locally from one-hot C (cheap, L2-resident)
    for (int n = tid; n < NV; n += 256) {
        const float* row = C + n * KC;
        int a = 0;
        #pragma unroll
        for (int c2 = 0; c2 < KC; ++c2) if (row[c2] > 0.5f) a = c2;
        asg[n] = a;
    }

    if (bid < 96) {
        // ---- GEMM block: 32(b) x 32(i) tile of mean = X @ (W .* Gexp)^T + b
        __shared__ float Gs[KC * KC];
        __shared__ float Xs[32][33];
        __shared__ float Ws[32][33];
        __shared__ float vred[8][32];
        __shared__ float wred[4];
        for (int l = tid; l < KC * KC; l += 256) Gs[l] = G[l];
        __syncthreads();
        const int it = bid & 15, bt = bid >> 4;
        const int i0 = it * 32, b0 = bt * 32;
        const int tx = tid & 31, ty = tid >> 5;
        float acc[4] = {0.f, 0.f, 0.f, 0.f};
        for (int kt = 0; kt < 16; ++kt) {
            const int k0 = kt * 32;
            #pragma unroll
            for (int p = 0; p < 4; ++p) {
                const int l = tid + p * 256;
                const int rr = l >> 5, cc = l & 31;
                Xs[rr][cc] = X[(b0 + rr) * NV + k0 + cc];
                const int ir = i0 + rr;
                // fold the cluster mask into the W tile at LDS-store time
                Ws[rr][cc] = W[ir * NV + k0 + cc] * Gs[asg[ir] * KC + asg[k0 + cc]];
            }
            __syncthreads();
            #pragma unroll
            for (int kk = 0; kk < 32; ++kk) {
                const float wv = Ws[tx][kk];
                #pragma unroll
                for (int r = 0; r < 4; ++r)
                    acc[r] += Xs[ty * 4 + r][kk] * wv;
            }
            __syncthreads();
        }
        const int i = i0 + tx;
        const float bi = bias[i];
        const int ci = asg[i];
        float* smG = wsF + WS_SM;
        float vpart = 0.f, mmpart = 0.f;
        #pragma unroll
        for (int r = 0; r < 4; ++r) {
            const float val = acc[r] + bi;
            vpart += val;
            mmpart += val * val;
            atomicAdd(&smG[(b0 + ty * 4 + r) * KC + ci], val);
        }
        vred[ty][tx] = vpart;
        for (int off = 32; off; off >>= 1) mmpart += __shfl_down(mmpart, off, 64);
        if ((tid & 63) == 0) wred[tid >> 6] = mmpart;
        __syncthreads();
        if (tid < 32) {
            float s = 0.f;
            #pragma unroll
            for (int q = 0; q < 8; ++q) s += vred[q][tid];
            atomicAdd(&wsF[WS_V + i0 + tid], s);
        }
        if (tid == 0) atomicAdd(&wsF[WS_MM], wred[0] + wred[1] + wred[2] + wred[3]);
    } else if (bid < 120) {
        // ---- X statistics block: 8 rows of X -> xx, u, cluster row-sums
        __shared__ float smrow[KC];
        __shared__ float xred[4];
        __syncthreads();
        const int sb = bid - 96;
        const int c0 = tid * 2;
        const int ca = asg[c0], cb = asg[c0 + 1];
        float u0 = 0.f, u1 = 0.f, xxloc = 0.f, sx1acc = 0.f, sx2acc = 0.f;
        for (int r = 0; r < 8; ++r) {
            const int row = sb * 8 + r;
            if (tid < KC) smrow[tid] = 0.f;
            __syncthreads();
            const float2 xv = *(const float2*)(X + row * NV + c0);
            u0 += xv.x; u1 += xv.y;
            xxloc += xv.x * xv.x + xv.y * xv.y;
            atomicAdd(&smrow[ca], xv.x);
            atomicAdd(&smrow[cb], xv.y);
            __syncthreads();
            if (tid < KC) { const float s = smrow[tid]; sx1acc += s; sx2acc += s * s; }
            __syncthreads();
        }
        atomicAdd(&wsF[WS_U + c0], u0);
        atomicAdd(&wsF[WS_U + c0 + 1], u1);
        if (tid < KC) {
            atomicAdd(&wsF[WS_SX1 + tid], sx1acc);
            atomicAdd(&wsF[WS_SX2 + tid], sx2acc);
        }
        for (int off = 32; off; off >>= 1) xxloc += __shfl_down(xxloc, off, 64);
        if ((tid & 63) == 0) xred[tid >> 6] = xxloc;
        __syncthreads();
        if (tid == 0) atomicAdd(&wsF[WS_XX], xred[0] + xred[1] + xred[2] + xred[3]);
    } else {
        // ---- prep block: counts, coef, logdet, persist assign
        __shared__ int cnt[KC];
        __shared__ float ldred[KC];
        if (tid < KC) cnt[tid] = 0;
        __syncthreads();
        for (int n = tid; n < NV; n += 256) {
            atomicAdd(&cnt[asg[n]], 1);
            wsI[n] = asg[n];
        }
        __syncthreads();
        const float s2 = sigma[0] * sigma[0];
        const float rh = rho[0];
        const float av = s2 * (1.f - rh), bv = s2 * rh;
        if (tid < KC) {
            const int nc = cnt[tid];
            wsF[WS_COEF + tid] = bv / (av * (av + bv * (float)nc));
            ldred[tid] = (float)(nc - 1) * logf(av) + logf(av + bv * (float)nc);
        }
        __syncthreads();
        if (tid == 0) {
            float ld = 0.f;
            for (int c2 = 0; c2 < KC; ++c2) ld += ldred[c2];
            wsF[WS_LOGDET] = ld;
        }
    }
}

__global__ __launch_bounds__(256) void final_kernel(
    const float* __restrict__ sigma, const float* __restrict__ rho,
    const float* __restrict__ wsF, float* __restrict__ out)
{
    const int tid = threadIdx.x;
    __shared__ float SM1s[KC], SM2s[KC];
    __shared__ float red1[8][KC], red2[8][KC];
    __shared__ float crW[4];
    __shared__ float qsh;
    const float* sm = wsF + WS_SM;
    const int c = tid & 31, g = tid >> 5;
    float s1 = 0.f, s2sum = 0.f;
    for (int b = g; b < NB; b += 8) {
        const float s = sm[b * KC + c];
        s1 += s; s2sum += s * s;
    }
    red1[g][c] = s1; red2[g][c] = s2sum;
    __syncthreads();
    if (tid < KC) {
        float a1 = 0.f, a2 = 0.f;
        #pragma unroll
        for (int q = 0; q < 8; ++q) { a1 += red1[q][tid]; a2 += red2[q][tid]; }
        SM1s[tid] = a1; SM2s[tid] = a2;
    }
    __syncthreads();
    // cross term u . v
    float cr = wsF[WS_U + tid] * wsF[WS_V + tid]
             + wsF[WS_U + 256 + tid] * wsF[WS_V + 256 + tid];
    for (int off = 32; off; off >>= 1) cr += __shfl_down(cr, off, 64);
    if ((tid & 63) == 0) crW[tid >> 6] = cr;
    // Q term
    float qv = 0.f;
    if (tid < KC) {
        const float coef = wsF[WS_COEF + tid];
        const float sx1 = wsF[WS_SX1 + tid], sx2 = wsF[WS_SX2 + tid];
        qv = coef * (sx2 * (1.f / NB) + SM2s[tid] * (1.f / NB)
                     - 2.f * sx1 * SM1s[tid] * (1.f / ((float)NB * (float)NB)));
    }
    for (int off = 16; off; off >>= 1) qv += __shfl_down(qv, off, 64);
    if (tid == 0) qsh = qv;
    __syncthreads();
    if (tid == 0) {
        const float crt = crW[0] + crW[1] + crW[2] + crW[3];
        const float s2 = sigma[0] * sigma[0];
        const float rh = rho[0];
        const float av = s2 * (1.f - rh);
        const float meanD2 = wsF[WS_XX] * (1.f / NB) + wsF[WS_MM] * (1.f / NB)
                           - 2.f * crt / ((float)NB * (float)NB);
        const float maha = meanD2 / av - qsh;
        out[0] = -0.5f * (maha + wsF[WS_LOGDET] + (float)NV * LOG2PI);
    }
}

extern "C" void kernel_launch(void* const* d_in, const int* in_sizes, int n_in,
                              void* d_out, int out_size, void* d_ws, size_t ws_size,
                              hipStream_t stream) {
    const float* X     = (const float*)d_in[0];
    const float* C     = (const float*)d_in[1];
    const float* G     = (const float*)d_in[2];
    const float* W     = (const float*)d_in[3];
    const float* b     = (const float*)d_in[4];
    const float* sigma = (const float*)d_in[5];
    const float* rho   = (const float*)d_in[6];
    float* wsF = (float*)d_ws;
    int*   wsI = (int*)d_ws;
    float* out = (float*)d_out;

    hipMemsetAsync(d_ws, 0, WS_TOTAL * sizeof(float), stream);
    hipLaunchKernelGGL(fused_kernel, dim3(121), dim3(256), 0, stream,
                       X, C, G, W, b, sigma, rho, wsF, wsI);
    hipLaunchKernelGGL(final_kernel, dim3(1), dim3(256), 0, stream,
                       sigma, rho, wsF, out);
}